// Round 4
// baseline (686.114 us; speedup 1.0000x reference)
//
#include <hip/hip_runtime.h>
#include <math.h>

#define CDIM 256
#define KDIM 1024
#define TOPK 8
#define MROWS 64
#define NELEM 16777216
#define L2E 1.4426950408889634f

typedef unsigned short u16;
typedef unsigned int u32;
typedef __attribute__((ext_vector_type(8))) short s16x8;
typedef __attribute__((ext_vector_type(8))) __bf16 b16x8;
typedef __attribute__((ext_vector_type(16))) float f32x16;

#define ZERO16 {0.f,0.f,0.f,0.f,0.f,0.f,0.f,0.f,0.f,0.f,0.f,0.f,0.f,0.f,0.f,0.f}

// ws layout (bytes)
#define WS_COUNTS 64
#define WS_DN     4608
#define WS_B2     8704
#define WS_WH     16384
#define WS_DH     (WS_WH + 524288)
#define WS_DL     (WS_DH + 524288)

// smem layout (bytes)
#define SM_XH   0
#define SM_XL   32768
#define SM_PD   65536
#define SM_PI   69632
#define SM_PM   73728
#define SM_PS   74240
#define SM_SELP 74752
#define SM_SELI 76800
#define SM_SELM 78848
#define SM_SELS 79104
#define SM_TOT  79360

__device__ __forceinline__ u16 f2bf(float f) {
    u32 u = __builtin_bit_cast(u32, f);
    u += 0x7FFFu + ((u >> 16) & 1u);
    return (u16)(u >> 16);
}
__device__ __forceinline__ float bf2f(u16 h) {
    return __builtin_bit_cast(float, ((u32)h) << 16);
}
__device__ __forceinline__ float hi2f(u32 u) {
    return __builtin_bit_cast(float, u & 0xFFFF0000u);
}
__device__ __forceinline__ f32x16 mfma16(s16x8 a, s16x8 b, f32x16 c) {
    return __builtin_amdgcn_mfma_f32_32x32x16_bf16(
        __builtin_bit_cast(b16x8, a), __builtin_bit_cast(b16x8, b), c, 0, 0, 0);
}

// branchless sorted-ascending insert of (key, idx); 5 VALU ops per position
#define INS2(DV, CI) { float cd_ = (DV); int ci_ = (CI); \
    _Pragma("unroll") \
    for (int p_ = 0; p_ < 8; ++p_) { \
        bool lt_ = cd_ < hd[p_]; \
        float nk_ = lt_ ? cd_ : hd[p_]; \
        float ok_ = lt_ ? hd[p_] : cd_; \
        int ni_ = lt_ ? ci_ : hix[p_]; \
        int oi_ = lt_ ? hix[p_] : ci_; \
        hd[p_] = nk_; cd_ = ok_; hix[p_] = ni_; ci_ = oi_; } }

#define CE(A, B) { \
    bool sw_ = (hd[B] < hd[A]) || (hd[B] == hd[A] && hix[B] < hix[A]); \
    if (sw_) { float td_ = hd[A]; hd[A] = hd[B]; hd[B] = td_; \
               int ti_ = hix[A]; hix[A] = hix[B]; hix[B] = ti_; } }

// merge sorted 8-list in od/oi into hd/hix (both sorted ascending)
#define MERGE8() { \
    _Pragma("unroll") \
    for (int j_ = 0; j_ < 8; ++j_) { \
        float bd_ = od[7 - j_]; int bi_ = oi[7 - j_]; \
        if (bd_ < hd[j_] || (bd_ == hd[j_] && bi_ < hix[j_])) { \
            hd[j_] = bd_; hix[j_] = bi_; } } \
    CE(0,4) CE(1,5) CE(2,6) CE(3,7) \
    CE(0,2) CE(1,3) CE(4,6) CE(5,7) \
    CE(0,1) CE(2,3) CE(4,5) CE(6,7) }

// ---------------- prepass: bf16 splits (log2e folded into W, -2 into D) ----
__global__ __launch_bounds__(256)
void dl_prep(const float* __restrict__ Wm, const float* __restrict__ dict,
             const float* __restrict__ bv,
             u16* __restrict__ Wh, u16* __restrict__ Dh, u16* __restrict__ Dl,
             float* __restrict__ dn, float* __restrict__ b2)
{
    __shared__ float red[4];
    const int k = blockIdx.x, c = threadIdx.x;
    const size_t idx = ((size_t)k << 8) + c;
    Wh[idx] = f2bf(Wm[idx] * L2E);
    float d = dict[idx];
    float v = -2.0f * d;
    u16 vh = f2bf(v);
    Dh[idx] = vh;
    Dl[idx] = f2bf(v - bf2f(vh));
    float sq = d * d;
    #pragma unroll
    for (int off = 32; off; off >>= 1) sq += __shfl_down(sq, off);
    if ((c & 63) == 0) red[c >> 6] = sq;
    __syncthreads();
    if (c == 0) { dn[k] = red[0] + red[1] + red[2] + red[3]; b2[k] = bv[k] * L2E; }
}

// ---------------- main fused kernel -----------------------------------------
__global__ __launch_bounds__(512, 4)
void dl_main(const float* __restrict__ x, const float* __restrict__ dict,
             const float* __restrict__ Wm, const float* __restrict__ bv,
             const u16* __restrict__ Wh, const u16* __restrict__ Dh,
             const u16* __restrict__ Dl, const float* __restrict__ dnp,
             const float* __restrict__ b2g, float* __restrict__ out,
             float* __restrict__ loss_acc, float* __restrict__ reg_acc,
             int* __restrict__ counts)
{
    __shared__ __align__(16) char smem[SM_TOT];
    u16*   xh   = (u16*)(smem + SM_XH);
    u16*   xl   = (u16*)(smem + SM_XL);
    float* pd   = (float*)(smem + SM_PD);
    int*   pi   = (int*)(smem + SM_PI);
    float* pm   = (float*)(smem + SM_PM);
    float* ps   = (float*)(smem + SM_PS);
    float* selp = (float*)(smem + SM_SELP);
    int*   seli = (int*)(smem + SM_SELI);
    float* selm = (float*)(smem + SM_SELM);
    float* sels = (float*)(smem + SM_SELS);

    const int t = threadIdx.x;
    const int lane = t & 63;
    const int wid = t >> 6;
    const int n0 = blockIdx.x * MROWS;

    // ---- phase 0: stage x -> bf16 hi/lo (swizzled)
    {
        const int r = t & 63, cs = t >> 6;
        const float* xb = x + ((size_t)(n0 >> 12) << 20) + (n0 & 4095) + r;
        #pragma unroll 4
        for (int i = 0; i < 32; i += 2) {
            int c = cs * 32 + i;
            float g0 = xb[(size_t)c << 12];
            float g1 = xb[(size_t)(c + 1) << 12];
            u16 h0 = f2bf(g0), h1 = f2bf(g1);
            u16 e0 = f2bf(g0 - bf2f(h0)), e1 = f2bf(g1 - bf2f(h1));
            int byte = (r * 512 + c * 2) ^ ((r & 7) << 4);
            *(u32*)((char*)xh + byte) = (u32)h0 | ((u32)h1 << 16);
            *(u32*)((char*)xl + byte) = (u32)e0 | ((u32)e1 << 16);
        }
    }
    __syncthreads();

    // ---- rep zero-fill early (fire-and-forget HBM writes overlap compute)
    float* rep0 = out + 2 + (size_t)NELEM;
    {
        float2* zb = (float2*)(rep0 + ((size_t)n0 << 10));
        #pragma unroll 8
        for (int i = 0; i < 64; ++i) zb[i * 512 + t] = make_float2(0.f, 0.f);
    }

    const int arow = lane & 31, hl = lane >> 5;
    const int rgrp = wid & 1, agrp = wid >> 1;
    const int xrow = rgrp * 32 + arow;
    const int swz = (arow & 7) << 4;

    float m_run = -INFINITY, s_run = 0.f;
    float hd[TOPK];
    int hix[TOPK];
    #pragma unroll
    for (int j = 0; j < TOPK; ++j) { hd[j] = INFINITY; hix[j] = 0; }

    // ---- barrier-free main loop: 8 chunks of 128 atoms
    #pragma unroll 1
    for (int ck = 0; ck < 8; ++ck) {
        const size_t arow_g = (size_t)(ck * 128 + agrp * 32 + arow);
        const u16* Wp  = Wh + (arow_g << 8) + hl * 8;
        const u16* Dhp = Dh + (arow_g << 8) + hl * 8;
        const u16* Dlp = Dl + (arow_g << 8) + hl * 8;

        f32x16 accL = ZERO16, accD = ZERO16;
        #pragma unroll 2
        for (int kst = 0; kst < 16; ++kst) {
            int boff = (xrow * 512 + hl * 16 + kst * 32) ^ swz;
            s16x8 aw  = *(const s16x8*)(Wp  + kst * 16);
            s16x8 adh = *(const s16x8*)(Dhp + kst * 16);
            s16x8 adl = *(const s16x8*)(Dlp + kst * 16);
            s16x8 bh = *(const s16x8*)((const char*)xh + boff);
            s16x8 bl = *(const s16x8*)((const char*)xl + boff);
            accL = mfma16(aw,  bh, accL);   // log2-domain logits (hi only)
            accD = mfma16(adh, bh, accD);   // -2 x_hi.d_hi
            accD = mfma16(adh, bl, accD);   // -2 x_lo.d_hi
            accD = mfma16(adl, bh, accD);   // -2 x_hi.d_lo
        }

        // consume: lane-local online softmax + top-8 (16 atoms per lane)
        #pragma unroll
        for (int rg = 0; rg < 4; ++rg) {
            const int mb = ck * 128 + agrp * 32 + 8 * rg + 4 * hl;
            float4 b4 = *(const float4*)(b2g + mb);
            float4 n4 = *(const float4*)(dnp + mb);
            float lv0 = accL[4*rg+0] + b4.x, lv1 = accL[4*rg+1] + b4.y;
            float lv2 = accL[4*rg+2] + b4.z, lv3 = accL[4*rg+3] + b4.w;
            float mx = fmaxf(fmaxf(fmaxf(lv0, lv1), fmaxf(lv2, lv3)), m_run);
            s_run = s_run * exp2f(m_run - mx)
                  + exp2f(lv0 - mx) + exp2f(lv1 - mx)
                  + exp2f(lv2 - mx) + exp2f(lv3 - mx);
            m_run = mx;
            // selection key: dn - 2 x.d  (row-constant ||x||^2 dropped)
            float dv0 = n4.x + accD[4*rg+0];
            float dv1 = n4.y + accD[4*rg+1];
            float dv2 = n4.z + accD[4*rg+2];
            float dv3 = n4.w + accD[4*rg+3];
            INS2(dv0, mb + 0)
            INS2(dv1, mb + 1)
            INS2(dv2, mb + 2)
            INS2(dv3, mb + 3)
        }
    }

    // ---- merge the two atom-halves (lane n <-> lane n+32): same x-row
    {
        float mo = __shfl_xor(m_run, 32);
        float so = __shfl_xor(s_run, 32);
        float mn = fmaxf(m_run, mo);
        s_run = s_run * exp2f(m_run - mn) + so * exp2f(mo - mn);
        m_run = mn;
        float od[TOPK]; int oi[TOPK];
        #pragma unroll
        for (int j = 0; j < TOPK; ++j) {
            od[j] = __shfl_xor(hd[j], 32);
            oi[j] = __shfl_xor(hix[j], 32);
        }
        MERGE8()
    }

    // ---- cross-wave merge (4 atom-groups -> 1)
    __syncthreads();
    if (wid >= 4 && lane < 32) {            // agrp 2,3 publish
        int base = ((agrp - 2) * 64 + xrow);
        #pragma unroll
        for (int j = 0; j < TOPK; ++j) {
            pd[base * 8 + j] = hd[j]; pi[base * 8 + j] = hix[j];
        }
        pm[base] = m_run; ps[base] = s_run;
    }
    __syncthreads();
    if (wid < 4 && lane < 32) {             // agrp 0,1 absorb agrp 2,3
        int base = (agrp * 64 + xrow);
        float od[TOPK]; int oi[TOPK];
        #pragma unroll
        for (int j = 0; j < TOPK; ++j) {
            od[j] = pd[base * 8 + j]; oi[j] = pi[base * 8 + j];
        }
        float mo = pm[base], so = ps[base];
        float mn = fmaxf(m_run, mo);
        s_run = s_run * exp2f(m_run - mn) + so * exp2f(mo - mn);
        m_run = mn;
        MERGE8()
    }
    __syncthreads();
    if ((wid == 2 || wid == 3) && lane < 32) {   // agrp1 publish
        #pragma unroll
        for (int j = 0; j < TOPK; ++j) {
            pd[xrow * 8 + j] = hd[j]; pi[xrow * 8 + j] = hix[j];
        }
        pm[xrow] = m_run; ps[xrow] = s_run;
    }
    __syncthreads();
    if (wid < 2 && lane < 32) {                  // agrp0 final merge
        float od[TOPK]; int oi[TOPK];
        #pragma unroll
        for (int j = 0; j < TOPK; ++j) {
            od[j] = pd[xrow * 8 + j]; oi[j] = pi[xrow * 8 + j];
        }
        float mo = pm[xrow], so = ps[xrow];
        float mn = fmaxf(m_run, mo);
        s_run = s_run * exp2f(m_run - mn) + so * exp2f(mo - mn);
        m_run = mn;
        MERGE8()
        selm[xrow] = m_run;
        sels[xrow] = 1.0f / s_run;
        #pragma unroll
        for (int j = 0; j < TOPK; ++j) {
            seli[xrow * 8 + j] = hix[j];
            atomicAdd(&counts[hix[j]], 1);
        }
    }
    __syncthreads();

    // ---- recompute winner logits exactly (fp32 W, b) -> probabilities
    {
        const int row = t >> 3, j = t & 7;
        const int idxw = seli[row * 8 + j];
        const float4* wp = (const float4*)(Wm + ((size_t)idxw << 8));
        const int swr = (row & 7) << 4;
        float4 a = make_float4(0.f, 0.f, 0.f, 0.f);
        #pragma unroll 4
        for (int i = 0; i < 32; ++i) {
            int byte = (row * 512 + i * 16) ^ swr;
            uint4 H = *(const uint4*)((const char*)xh + byte);
            uint4 L = *(const uint4*)((const char*)xl + byte);
            float4 w0 = wp[i * 2], w1 = wp[i * 2 + 1];
            a.x += (bf2f((u16)H.x) + bf2f((u16)L.x)) * w0.x;
            a.y += (hi2f(H.x) + hi2f(L.x)) * w0.y;
            a.z += (bf2f((u16)H.y) + bf2f((u16)L.y)) * w0.z;
            a.w += (hi2f(H.y) + hi2f(L.y)) * w0.w;
            a.x += (bf2f((u16)H.z) + bf2f((u16)L.z)) * w1.x;
            a.y += (hi2f(H.z) + hi2f(L.z)) * w1.y;
            a.z += (bf2f((u16)H.w) + bf2f((u16)L.w)) * w1.z;
            a.w += (hi2f(H.w) + hi2f(L.w)) * w1.w;
        }
        float lg = (a.x + a.y) + (a.z + a.w) + bv[idxw];
        float p = exp2f(lg * L2E - selm[row]) * sels[row];
        selp[row * 8 + j] = p;
        float v2 = p;
        #pragma unroll
        for (int off = 32; off; off >>= 1) v2 += __shfl_down(v2, off);
        if (lane == 0) atomicAdd(reg_acc, v2);
    }
    __syncthreads();

    // ---- rep scatter
    {
        int rr = t >> 3, j = t & 7;
        rep0[((size_t)(n0 + rr) << 10) + seli[rr * 8 + j]] = selp[rr * 8 + j];
    }

    // ---- recon (flat .view semantics) + fused MSE (x rebuilt from LDS hi+lo)
    float lsum = 0.f;
    {
        int rr = t >> 3, tl = t & 7;
        size_t n = (size_t)(n0 + rr);
        const int swr = (rr & 7) << 4;
        float acc[32];
        #pragma unroll
        for (int i = 0; i < 32; ++i) acc[i] = 0.f;
        #pragma unroll
        for (int j = 0; j < TOPK; ++j) {
            float p = selp[rr * 8 + j];
            const float* dp = dict + ((size_t)seli[rr * 8 + j] << 8) + tl * 32;
            #pragma unroll
            for (int i = 0; i < 32; i += 4) {
                float4 d4 = *(const float4*)(dp + i);
                acc[i]     += p * d4.x; acc[i + 1] += p * d4.y;
                acc[i + 2] += p * d4.z; acc[i + 3] += p * d4.w;
            }
        }
        float* ro = out + 1 + (n << 8) + tl * 32;
        #pragma unroll
        for (int i = 0; i < 4; ++i) {
            int byte = (rr * 512 + tl * 64 + i * 16) ^ swr;
            uint4 H = *(const uint4*)((const char*)xh + byte);
            uint4 L = *(const uint4*)((const char*)xl + byte);
            float xv[8];
            xv[0] = bf2f((u16)H.x) + bf2f((u16)L.x);
            xv[1] = hi2f(H.x) + hi2f(L.x);
            xv[2] = bf2f((u16)H.y) + bf2f((u16)L.y);
            xv[3] = hi2f(H.y) + hi2f(L.y);
            xv[4] = bf2f((u16)H.z) + bf2f((u16)L.z);
            xv[5] = hi2f(H.z) + hi2f(L.z);
            xv[6] = bf2f((u16)H.w) + bf2f((u16)L.w);
            xv[7] = hi2f(H.w) + hi2f(L.w);
            #pragma unroll
            for (int q = 0; q < 8; ++q) {
                float av = acc[i * 8 + q];
                float e = xv[q] - av;
                lsum += e * e;
                ro[i * 8 + q] = av;
            }
        }
    }
    {
        #pragma unroll
        for (int off = 32; off; off >>= 1) lsum += __shfl_down(lsum, off);
        if (lane == 0) atomicAdd(loss_acc, lsum);
    }
}

// ---------------- finalize scalars -------------------------------------------
__global__ void dl_final(const float* __restrict__ loss_acc,
                         const float* __restrict__ reg_acc,
                         const int* __restrict__ counts,
                         float* __restrict__ out)
{
    __shared__ float red[4];
    int t = threadIdx.x;
    float e = 0.f;
    for (int k = t; k < KDIM; k += 256) {
        float p = (float)counts[k] * (1.0f / 524288.0f);
        e += p * logf(p + 1e-10f);
    }
    #pragma unroll
    for (int off = 32; off; off >>= 1) e += __shfl_down(e, off);
    if ((t & 63) == 0) red[t >> 6] = e;
    __syncthreads();
    if (t == 0) {
        float et = red[0] + red[1] + red[2] + red[3];
        out[(size_t)NELEM + 1] = __expf(-et);                     // perplexity
        out[0] = 2.0f * loss_acc[0] / (float)NELEM + reg_acc[0];  // loss + reg
    }
}

extern "C" void kernel_launch(void* const* d_in, const int* in_sizes, int n_in,
                              void* d_out, int out_size, void* d_ws, size_t ws_size,
                              hipStream_t stream) {
    const float* x    = (const float*)d_in[0];
    const float* dict = (const float*)d_in[1];
    const float* Wm   = (const float*)d_in[2];
    const float* bv   = (const float*)d_in[3];
    float* out = (float*)d_out;

    float* loss_acc = (float*)d_ws;
    float* reg_acc  = loss_acc + 1;
    int*   counts   = (int*)((char*)d_ws + WS_COUNTS);
    float* dn       = (float*)((char*)d_ws + WS_DN);
    float* b2       = (float*)((char*)d_ws + WS_B2);
    u16*   Wh       = (u16*)((char*)d_ws + WS_WH);
    u16*   Dh       = (u16*)((char*)d_ws + WS_DH);
    u16*   Dl       = (u16*)((char*)d_ws + WS_DL);

    hipMemsetAsync(d_ws, 0, 4608, stream);
    dl_prep<<<KDIM, 256, 0, stream>>>(Wm, dict, bv, Wh, Dh, Dl, dn, b2);
    dl_main<<<65536 / MROWS, 512, 0, stream>>>(x, dict, Wm, bv, Wh, Dh, Dl, dn,
                                               b2, out, loss_acc, reg_acc, counts);
    dl_final<<<1, 256, 0, stream>>>(loss_acc, reg_acc, counts, out);
}